// Round 1
// 292.702 us; speedup vs baseline: 1.0460x; 1.0460x over previous
//
#include <hip/hip_runtime.h>
#include <math.h>

#define NDET 512
#define NCLS 81
#define MM   784      // 28*28
#define PROBS_ELEMS (2 * NDET * MM)   // 802816
#define NMS_TH 0.5
#define EPS_D  1e-4
#define SDD 114       // LDS row stride in DOUBLES: even (16B-aligned double2),
                      // bank-pair stride 4 -> worst 2-way aliasing (free, m136)

// ---------------- ws layout (bytes) ----------------
// 0      : double u[2][512]            (8192)
// 8192   : int order[512]              (2048)
// 16384  : u32 bits32[2][512][16]      (65536)   == u64 bits[2][512][8]
// total  : 81920 bytes

// K12: blocks 0..255 -> gather+sigmoid, one WAVE per (side,detection) mask
//      (4 masks/block, shfl reduction, no barriers).
//      block 256 -> single-block bitonic sort of scores (runs concurrently).
__global__ __launch_bounds__(256) void k12_fused(
    const float* __restrict__ left, const float* __restrict__ right,
    const float* __restrict__ scores, const int* __restrict__ labels,
    float* __restrict__ out, double* __restrict__ u, int* __restrict__ order) {
  if (blockIdx.x == 256) {
    // ---- bitonic sort of 512 (score desc, idx asc), 256 threads ----
    __shared__ float sk[NDET];
    __shared__ int   si[NDET];
    int t = threadIdx.x;
    for (int e = t; e < NDET; e += 256) { sk[e] = scores[e]; si[e] = e; }
    __syncthreads();
    for (int k = 2; k <= NDET; k <<= 1) {
      for (int j = k >> 1; j > 0; j >>= 1) {
        for (int e = t; e < NDET; e += 256) {
          int p = e ^ j;
          if (p > e) {
            bool dir = ((e & k) == 0);   // descending block
            float sa = sk[e], sb = sk[p];
            int ia = si[e], ib = si[p];
            bool aBeforeB = (sa > sb) || (sa == sb && ia < ib);
            bool doSwap = dir ? (!aBeforeB) : aBeforeB;
            if (doSwap) { sk[e] = sb; si[e] = ib; sk[p] = sa; si[p] = ia; }
          }
        }
        __syncthreads();
      }
    }
    for (int e = t; e < NDET; e += 256) order[e] = si[e];
    return;
  }

  // ---- gather + sigmoid + fp64 row-sum, one wave per mask ----
  int wv = threadIdx.x >> 6;
  int lane = threadIdx.x & 63;
  int m = (blockIdx.x << 2) | wv;     // 0..1023
  int s = m >> 9;                     // side
  int n = m & 511;                    // detection
  const float* src = (s == 0) ? left : right;
  int lab = labels[n];
  const float4* in4 = (const float4*)(src + ((size_t)n * NCLS + lab) * MM);
  float4* out4 = (float4*)(out + ((size_t)s * NDET + n) * MM);
  double local = 0.0;
  for (int i = lane; i < MM / 4; i += 64) {   // 196 float4
    float4 v = in4[i];
    float4 r;
    r.x = 1.0f / (1.0f + expf(-v.x));
    r.y = 1.0f / (1.0f + expf(-v.y));
    r.z = 1.0f / (1.0f + expf(-v.z));
    r.w = 1.0f / (1.0f + expf(-v.w));
    out4[i] = r;
    local += (double)r.x + (double)r.y + (double)r.z + (double)r.w;
  }
#pragma unroll
  for (int off = 32; off > 0; off >>= 1)
    local += __shfl_down(local, off, 64);
  if (lane == 0) u[s * NDET + n] = local;
}

// K3: upper-triangular 32x32 tiles of the sorted iou comparison matrix.
// DOUBLE-typed LDS staging (convert f32->f64 once per element, 16x fewer cvts
// than converting per-use), 2x2 register tiling, ds_read_b128 double2 reads,
// fp64 accumulate, ballot-packed 32-bit column-mask output.
__global__ __launch_bounds__(256) void k3_iou(
    const float* __restrict__ P,        // d_out probs base (2*512*784 f32)
    const double* __restrict__ u,
    const int* __restrict__ order,
    unsigned int* __restrict__ bits32) {
  int bi = blockIdx.x;                  // 0..271
  int s = bi / 136;
  int tri = bi % 136;
  int ti = 0, rem = tri;
  while (rem >= 16 - ti) { rem -= 16 - ti; ti++; }
  int tj = ti + rem;                    // tj >= ti

  __shared__ __align__(16) double Asd[32][SDD];
  __shared__ __align__(16) double Bsd[32][SDD];
  __shared__ int oi[32], oj[32];
  __shared__ double den[32];

  int t = threadIdx.x;
  if (t < 32) {
    int r = order[ti * 32 + t];
    oi[t] = r;
    den[t] = u[s * NDET + r] + EPS_D;
    oj[t] = order[tj * 32 + t];
  }
  __syncthreads();

  const float* Pside = P + (size_t)s * NDET * MM;
  int cx = t & 15;          // column sub-index (fastest-varying within wave)
  int ry = t >> 4;          // row sub-index 0..15
  double a00 = 0.0, a01 = 0.0, a10 = 0.0, a11 = 0.0;

  for (int kc = 0; kc < 7; kc++) {      // 7 * 112 = 784
    int k0 = kc * 112;
    // stage 32 rows x 112 cols of A and B, converting to double once.
    for (int e = t; e < 32 * 28; e += 256) {   // 28 float4 per row
      int r = e / 28;
      int c4 = e - r * 28;
      float4 va = *(const float4*)&Pside[(size_t)oi[r] * MM + k0 + 4 * c4];
      float4 vb = *(const float4*)&Pside[(size_t)oj[r] * MM + k0 + 4 * c4];
      double2 a0; a0.x = (double)va.x; a0.y = (double)va.y;
      double2 a1; a1.x = (double)va.z; a1.y = (double)va.w;
      double2 b0; b0.x = (double)vb.x; b0.y = (double)vb.y;
      double2 b1; b1.x = (double)vb.z; b1.y = (double)vb.w;
      *(double2*)&Asd[r][4 * c4]     = a0;
      *(double2*)&Asd[r][4 * c4 + 2] = a1;
      *(double2*)&Bsd[r][4 * c4]     = b0;
      *(double2*)&Bsd[r][4 * c4 + 2] = b1;
    }
    __syncthreads();
    for (int kp = 0; kp < 56; kp++) {
      double2 fa0 = *(const double2*)&Asd[ry][2 * kp];
      double2 fa1 = *(const double2*)&Asd[ry + 16][2 * kp];
      double2 fb0 = *(const double2*)&Bsd[cx][2 * kp];
      double2 fb1 = *(const double2*)&Bsd[cx + 16][2 * kp];
      a00 += fa0.x * fb0.x; a00 += fa0.y * fb0.y;
      a01 += fa0.x * fb1.x; a01 += fa0.y * fb1.y;
      a10 += fa1.x * fb0.x; a10 += fa1.y * fb0.y;
      a11 += fa1.x * fb1.x; a11 += fa1.y * fb1.y;
    }
    __syncthreads();
  }

  // rows i0 = ti*32+ry, i1 = ti*32+ry+16; cols tj*32 + {cx, cx+16}
  bool p00 = (a00 / den[ry]      >= NMS_TH);
  bool p01 = (a01 / den[ry]      >= NMS_TH);
  bool p10 = (a10 / den[ry + 16] >= NMS_TH);
  bool p11 = (a11 / den[ry + 16] >= NMS_TH);
  unsigned long long bl0 = __ballot(p00);
  unsigned long long bh0 = __ballot(p01);
  unsigned long long bl1 = __ballot(p10);
  unsigned long long bh1 = __ballot(p11);
  int q = ry & 3;                       // 16-lane group within the wave
  if (cx == 0) {
    unsigned m0 = (unsigned)((bl0 >> (16 * q)) & 0xffffull) |
                  ((unsigned)((bh0 >> (16 * q)) & 0xffffull) << 16);
    unsigned m1 = (unsigned)((bl1 >> (16 * q)) & 0xffffull) |
                  ((unsigned)((bh1 >> (16 * q)) & 0xffffull) << 16);
    bits32[((size_t)s * NDET + ti * 32 + ry) * 16 + tj] = m0;
    bits32[((size_t)s * NDET + ti * 32 + ry + 16) * 16 + tj] = m1;
  }
}

// K4: greedy suppression (both sides) + combine. One block, 512 threads.
// Every lane of wave 0/1 holds the FULL 512-bit suppression mask in 8 u64
// registers (redundantly identical across lanes) -> active check is a
// register bit-test + scalar branch; suppressed rows cost ~8 instructions.
__global__ __launch_bounds__(512) void k4_greedy(
    const unsigned long long* __restrict__ bits,  // [2][512][8]
    const int* __restrict__ order,
    const double* __restrict__ u,
    float* __restrict__ outKeep) {
  __shared__ unsigned long long B[2 * NDET * 8];   // 64 KiB
  __shared__ unsigned char keepO[2 * NDET];        // by original index
  int t = threadIdx.x;

  // stage + mask j<=i (also kills garbage from never-written lower tiles)
  for (int e = t; e < 2 * NDET * 8; e += 512) {
    unsigned long long w = bits[e];
    int g = e & 7;
    int i = (e >> 3) & 511;
    int gi = i >> 6;
    if (g < gi) {
      w = 0ull;
    } else if (g == gi) {
      int li = i & 63;
      w = (li == 63) ? 0ull : (w & (~0ull << (li + 1)));
    }
    B[e] = w;
  }
  __syncthreads();

  int wv = t >> 6;
  int lane = t & 63;
  if (wv < 2) {
    int s = wv;
    const unsigned long long* Bside = B + (size_t)s * NDET * 8;
    unsigned long long S0 = 0, S1 = 0, S2 = 0, S3 = 0,
                       S4 = 0, S5 = 0, S6 = 0, S7 = 0;

#define GROUP(G, SG, ORS)                                              \
    for (int li = 0; li < 64; li++) {                                  \
      unsigned act = (unsigned)((SG >> li) & 1ull);                    \
      if (__builtin_amdgcn_readfirstlane(act) == 0) {                  \
        const unsigned long long* row = Bside + ((((G) << 6) | li) << 3); \
        ORS                                                            \
      }                                                                \
    }
    GROUP(0, S0, { S0 |= row[0]; S1 |= row[1]; S2 |= row[2]; S3 |= row[3];
                   S4 |= row[4]; S5 |= row[5]; S6 |= row[6]; S7 |= row[7]; })
    GROUP(1, S1, { S1 |= row[1]; S2 |= row[2]; S3 |= row[3];
                   S4 |= row[4]; S5 |= row[5]; S6 |= row[6]; S7 |= row[7]; })
    GROUP(2, S2, { S2 |= row[2]; S3 |= row[3];
                   S4 |= row[4]; S5 |= row[5]; S6 |= row[6]; S7 |= row[7]; })
    GROUP(3, S3, { S3 |= row[3];
                   S4 |= row[4]; S5 |= row[5]; S6 |= row[6]; S7 |= row[7]; })
    GROUP(4, S4, { S4 |= row[4]; S5 |= row[5]; S6 |= row[6]; S7 |= row[7]; })
    GROUP(5, S5, { S5 |= row[5]; S6 |= row[6]; S7 |= row[7]; })
    GROUP(6, S6, { S6 |= row[6]; S7 |= row[7]; })
    GROUP(7, S7, { S7 |= row[7]; })
#undef GROUP

    unsigned long long Sarr[8] = {S0, S1, S2, S3, S4, S5, S6, S7};
#pragma unroll
    for (int g = 0; g < 8; g++) {
      int c = (g << 6) | lane;                    // sorted position
      keepO[s * NDET + order[c]] =
          (unsigned char)(((Sarr[g] >> lane) & 1ull) ^ 1ull);
    }
  }
  __syncthreads();

  if (t < NDET) {
    bool valid = (u[t] > 0.0) && (u[NDET + t] > 0.0);
    outKeep[t] = (valid && keepO[t] && keepO[NDET + t]) ? 1.0f : 0.0f;
  }
}

extern "C" void kernel_launch(void* const* d_in, const int* in_sizes, int n_in,
                              void* d_out, int out_size, void* d_ws, size_t ws_size,
                              hipStream_t stream) {
  const float* left   = (const float*)d_in[0];
  const float* right  = (const float*)d_in[1];
  const float* scores = (const float*)d_in[2];
  const int*   labels = (const int*)d_in[3];
  float* out = (float*)d_out;

  char* ws = (char*)d_ws;
  double* u                = (double*)(ws + 0);
  int* order               = (int*)(ws + 8192);
  unsigned int* bits32     = (unsigned int*)(ws + 16384);
  unsigned long long* bits = (unsigned long long*)(ws + 16384);

  k12_fused<<<257, 256, 0, stream>>>(left, right, scores, labels, out, u, order);
  k3_iou<<<272, 256, 0, stream>>>(out, u, order, bits32);
  k4_greedy<<<1, 512, 0, stream>>>(bits, order, u, out + PROBS_ELEMS);
}